// Round 9
// baseline (11859.420 us; speedup 1.0000x reference)
//
#include <hip/hip_runtime.h>
#include <stdint.h>

#define S_LEN 1024
#define B_N   128
#define E_N   10
#define H_N   256
#define L_N   4
#define G4    1024   // 4*H

using short8 = __attribute__((ext_vector_type(8))) short;
using f32x4  = __attribute__((ext_vector_type(4))) float;

__device__ __forceinline__ unsigned short f2bf(float x){
    unsigned int u = __builtin_bit_cast(unsigned int, x);
    u = (u + 0x7FFFu + ((u >> 16) & 1u)) >> 16;   // RNE
    return (unsigned short)u;
}

__device__ __forceinline__ float fast_sig(float x){
    return 1.f/(1.f + __expf(-x));
}
__device__ __forceinline__ float fast_tanh(float x){
    float xc = fminf(fmaxf(x, -15.f), 15.f);
    float e = __expf(-2.f*xc);
    return (1.f - e)/(1.f + e);
}

// ---- convert f32 weights -> bf16 ----
__global__ void k_cvt(const float* __restrict__ src, unsigned short* __restrict__ dst, int n){
    int i = blockIdx.x*256 + threadIdx.x;
    if (i < n) dst[i] = f2bf(src[i]);
}

// ---- s[t][b][e] = relu((e01[x]+p01[t]) @ f01_w.T + f01_b) ----
__global__ void k_prep_s(const int* __restrict__ x, const float* __restrict__ e01,
                         const float* __restrict__ p01, const float* __restrict__ f01w,
                         const float* __restrict__ f01b, float* __restrict__ s){
    int idx = blockIdx.x*256 + threadIdx.x;   // t*128+b
    int t = idx >> 7;
    int tok = x[idx];
    float v[E_N];
    #pragma unroll
    for (int e=0;e<E_N;e++) v[e] = e01[tok*E_N+e] + p01[t*E_N+e];
    #pragma unroll
    for (int eo=0;eo<E_N;eo++){
        float a = f01b[eo];
        #pragma unroll
        for (int e=0;e<E_N;e++) a += v[e]*f01w[eo*E_N+e];
        s[(size_t)idx*E_N+eo] = a > 0.f ? a : 0.f;
    }
}

// ---- ssum[b][e] = sum_t s[t][b][e] ----
__global__ void k_ssum(const float* __restrict__ s, float* __restrict__ ssum){
    __shared__ float red[256][E_N];
    int b = blockIdx.x; int tid = threadIdx.x;
    float acc[E_N] = {};
    for (int t = tid; t < S_LEN; t += 256){
        const float* p = s + ((size_t)t*B_N + b)*E_N;
        #pragma unroll
        for (int e=0;e<E_N;e++) acc[e] += p[e];
    }
    #pragma unroll
    for (int e=0;e<E_N;e++) red[tid][e] = acc[e];
    __syncthreads();
    for (int st=128; st>0; st>>=1){
        if (tid < st){
            #pragma unroll
            for (int e=0;e<E_N;e++) red[tid][e] += red[tid+st][e];
        }
        __syncthreads();
    }
    if (tid < E_N) ssum[b*E_N+tid] = red[0][tid];
}

// ---- h0/c0 (relu MLPs on ssum), scatter into state buffers ----
__global__ void k_init(const float* __restrict__ ssum, const float* __restrict__ f02w,
                       const float* __restrict__ f02b, const float* __restrict__ f03w,
                       const float* __restrict__ f03b,
                       unsigned short* __restrict__ Hbuf, float* __restrict__ C){
    int b = blockIdx.x, j = threadIdx.x;   // j in [0,1024)
    float sv[E_N];
    #pragma unroll
    for (int e=0;e<E_N;e++) sv[e] = ssum[b*E_N+e];
    float h = f02b[j], c = f03b[j];
    #pragma unroll
    for (int e=0;e<E_N;e++){ h += sv[e]*f02w[j*E_N+e]; c += sv[e]*f03w[j*E_N+e]; }
    h = h > 0.f ? h : 0.f;
    c = c > 0.f ? c : 0.f;
    int l = j >> 8, k = j & 255;
    // layer l is first read at wall-step w=l from parity (l&1)
    Hbuf[(((size_t)l*2 + (l&1))*B_N + b)*H_N + k] = f2bf(h);
    C[((size_t)l*B_N + b)*H_N + k] = c;
}

// ---- bias sum + zero the sync flags ----
__global__ void k_bias(const float* __restrict__ bih, const float* __restrict__ bhh,
                       float* __restrict__ bsum, int* __restrict__ flags){
    int i = blockIdx.x*256 + threadIdx.x;   // 4096
    bsum[i] = bih[i] + bhh[i];
    if (i < 512) flags[i] = 0;
}

// ---- coherence-point (sc0 sc1) access helpers ----
__device__ __forceinline__ void coh_load8_nw(const unsigned short* p,
    uint4& d0, uint4& d1, uint4& d2, uint4& d3,
    uint4& d4, uint4& d5, uint4& d6, uint4& d7){
    asm volatile(
        "global_load_dwordx4 %0, %8, off sc0 sc1\n\t"
        "global_load_dwordx4 %1, %8, off offset:64 sc0 sc1\n\t"
        "global_load_dwordx4 %2, %8, off offset:128 sc0 sc1\n\t"
        "global_load_dwordx4 %3, %8, off offset:192 sc0 sc1\n\t"
        "global_load_dwordx4 %4, %8, off offset:256 sc0 sc1\n\t"
        "global_load_dwordx4 %5, %8, off offset:320 sc0 sc1\n\t"
        "global_load_dwordx4 %6, %8, off offset:384 sc0 sc1\n\t"
        "global_load_dwordx4 %7, %8, off offset:448 sc0 sc1"
        : "=&v"(d0), "=&v"(d1), "=&v"(d2), "=&v"(d3),
          "=&v"(d4), "=&v"(d5), "=&v"(d6), "=&v"(d7)
        : "v"(p) : "memory");
}
__device__ __forceinline__ void wait_vm0_fence(){
    asm volatile("s_waitcnt vmcnt(0)" ::: "memory");
    __builtin_amdgcn_sched_barrier(0);     // rule #18: pin consumers after the wait
}
__device__ __forceinline__ void coh_store4_short(unsigned short* p,
    unsigned int v0, unsigned int v1, unsigned int v2, unsigned int v3){
    // 4 batch rows, row stride 256 shorts = 512 B
    asm volatile(
        "global_store_short %0, %1, off sc0 sc1\n\t"
        "global_store_short %0, %2, off offset:512 sc0 sc1\n\t"
        "global_store_short %0, %3, off offset:1024 sc0 sc1\n\t"
        "global_store_short %0, %4, off offset:1536 sc0 sc1"
        :: "v"(p), "v"(v0), "v"(v1), "v"(v2), "v"(v3) : "memory");
}
__device__ __forceinline__ void coh_store_u32(int* p, int v){
    asm volatile("global_store_dword %0, %1, off sc0 sc1" :: "v"(p), "v"(v) : "memory");
}
__device__ __forceinline__ unsigned int coh_load_u32(const int* p){
    unsigned int v;
    asm volatile("global_load_dword %0, %1, off sc0 sc1\n\ts_waitcnt vmcnt(0)"
                 : "=v"(v) : "v"(p) : "memory");
    return v;
}
__device__ __forceinline__ void drain_vmem(){
    asm volatile("s_waitcnt vmcnt(0)" ::: "memory");
}

// ---- persistent wavefront LSTM ----
// grid 128 WGs: bg = bid&7, kj = (bid>>3)&3, l = bid>>5 ; block 256 = 4 waves.
// Wave owns 16 k-cols x 4 gates (in-register cell update, no LDS).
// Weights loaded in-loop (low VGPR). Sync: round-3-validated block protocol
// (flag+guard based — co-residency suffices; cooperative semantics not required).
__global__ __launch_bounds__(256) void k_lstm(
    const float* __restrict__ s,            // [S][B][E] f32
    const unsigned short* __restrict__ Wih, // [3][1024][256] bf16 (layers 1..3)
    const unsigned short* __restrict__ Whh, // [4][1024][256] bf16
    const float* __restrict__ Wih0,         // [1024][10] f32
    const float* __restrict__ bsum,         // [4][1024] f32
    unsigned short* __restrict__ Hbuf,      // [4][2][128][256] bf16
    const float* __restrict__ C,            // [4][128][256] f32 (init only)
    float* __restrict__ y,                  // [128][1024] f32 out
    int* flags)                             // [8][16] per-WG step flags
{
    const int bid = blockIdx.x;
    const int bg = bid & 7, kj = (bid >> 3) & 3, l = bid >> 5;
    const int tid = threadIdx.x;
    const int wv = tid >> 6, lane = tid & 63;
    const int cl = lane & 15, kg = lane >> 4;
    const int b0 = bg*16;
    const int kb = kj*64 + wv*16;           // wave's 16-col k base
    const size_t BH = (size_t)B_N * H_N;
    const int lm1 = (l > 0) ? (l - 1) : 0;

    // ---- per-gate weight row base pointers (pointers only; data loaded in-loop) ----
    const unsigned short* whp[4];
    const unsigned short* wip[4];
    const float*          w0p[4];
    #pragma unroll
    for (int g=0; g<4; g++){
        const int j = g*256 + kb + cl;
        whp[g] = Whh  + ((size_t)l*G4   + j)*H_N + kg*8;
        wip[g] = Wih  + ((size_t)lm1*G4 + j)*H_N + kg*8;
        w0p[g] = Wih0 + (size_t)j*E_N;
    }
    const float* biap = bsum + l*G4 + kb + cl;   // + g*256 in-loop

    // ---- private cell state: (batch=kg*4+r, col=kb+cl), 4 per lane ----
    float c[4];
    #pragma unroll
    for (int r=0; r<4; r++)
        c[r] = C[((size_t)l*B_N + b0 + kg*4 + r)*H_N + kb + cl];

    int* const wgflag = flags + bg*16 + l*4 + kj;       // one flag per WG
    const int* const bgflags = flags + bg*16;

    // A-frag row pointers: row = b0+cl (batch), k-offset kg*8 (A: row=lane&15, k=(lane>>4)*8+j)
    const unsigned short* const hload_row = Hbuf + (size_t)l*2*BH   + (size_t)(b0+cl)*H_N + kg*8;
    const unsigned short* const xload_row = Hbuf + (size_t)lm1*2*BH + (size_t)(b0+cl)*H_N + kg*8;
    unsigned short* const hstore_base = Hbuf + (size_t)l*2*BH + (size_t)(b0+kg*4)*H_N + kb + cl;

    for (int w = 0; w < S_LEN + L_N - 1; ++w){
        const int t = w - l;
        const int p = w & 1;
        if (t >= 0 && t < S_LEN){
            uint4 h0,h1,h2,h3,h4,h5,h6,h7;
            coh_load8_nw(hload_row + (size_t)p*BH, h0,h1,h2,h3,h4,h5,h6,h7);
            uint4 x0,x1,x2,x3,x4,x5,x6,x7;
            float xs[4][E_N];
            if (l > 0){
                coh_load8_nw(xload_row + (size_t)p*BH, x0,x1,x2,x3,x4,x5,x6,x7);
            } else {
                #pragma unroll
                for (int r=0; r<4; r++){
                    const float* sp = s + ((size_t)t*B_N + b0 + kg*4 + r)*E_N;
                    #pragma unroll
                    for (int e=0; e<E_N; e++) xs[r][e] = sp[e];
                }
            }
            wait_vm0_fence();

            f32x4 acc[4];
            #pragma unroll
            for (int g=0; g<4; g++){
                const float bg_ = biap[g*256];
                acc[g] = (f32x4){bg_, bg_, bg_, bg_};
            }

            short8 ah[8];
            ah[0]=__builtin_bit_cast(short8,h0); ah[1]=__builtin_bit_cast(short8,h1);
            ah[2]=__builtin_bit_cast(short8,h2); ah[3]=__builtin_bit_cast(short8,h3);
            ah[4]=__builtin_bit_cast(short8,h4); ah[5]=__builtin_bit_cast(short8,h5);
            ah[6]=__builtin_bit_cast(short8,h6); ah[7]=__builtin_bit_cast(short8,h7);
            #pragma unroll
            for (int g=0; g<4; g++)
                #pragma unroll
                for (int kt=0; kt<8; kt++){
                    short8 wt = *(const short8*)(whp[g] + kt*32);   // in-loop weight load
                    acc[g] = __builtin_amdgcn_mfma_f32_16x16x32_bf16(ah[kt], wt, acc[g], 0,0,0);
                }

            if (l > 0){
                short8 ax[8];
                ax[0]=__builtin_bit_cast(short8,x0); ax[1]=__builtin_bit_cast(short8,x1);
                ax[2]=__builtin_bit_cast(short8,x2); ax[3]=__builtin_bit_cast(short8,x3);
                ax[4]=__builtin_bit_cast(short8,x4); ax[5]=__builtin_bit_cast(short8,x5);
                ax[6]=__builtin_bit_cast(short8,x6); ax[7]=__builtin_bit_cast(short8,x7);
                #pragma unroll
                for (int g=0; g<4; g++)
                    #pragma unroll
                    for (int kt=0; kt<8; kt++){
                        short8 wt = *(const short8*)(wip[g] + kt*32);
                        acc[g] = __builtin_amdgcn_mfma_f32_16x16x32_bf16(ax[kt], wt, acc[g], 0,0,0);
                    }
            } else {
                #pragma unroll
                for (int g=0; g<4; g++)
                    #pragma unroll
                    for (int r=0; r<4; r++){
                        float v = acc[g][r];
                        #pragma unroll
                        for (int e=0; e<E_N; e++) v += xs[r][e]*w0p[g][e];  // in-loop
                        acc[g][r] = v;
                    }
            }

            // ---- in-register cell update (i,f,g,o of one element live in same lane/reg) ----
            unsigned int hbits[4];
            float hval[4];
            #pragma unroll
            for (int r=0; r<4; r++){
                float gi = fast_sig(acc[0][r]);
                float gf = fast_sig(acc[1][r]);
                float gg = fast_tanh(acc[2][r]);
                float go = fast_sig(acc[3][r]);
                c[r] = gf*c[r] + gi*gg;
                float hn = go*fast_tanh(c[r]);
                hval[r] = hn;
                hbits[r] = f2bf(hn);
            }
            coh_store4_short(hstore_base + (size_t)(p^1)*BH,
                             hbits[0], hbits[1], hbits[2], hbits[3]);
            if (t == S_LEN-1){
                #pragma unroll
                for (int r=0; r<4; r++)
                    y[(size_t)(b0+kg*4+r)*G4 + l*H_N + kb + cl] = hval[r];
            }
        }
        // ---- round-3-validated block-level sync protocol ----
        drain_vmem();          // every wave: its h stores acked at coherence point
        __syncthreads();       // all 4 waves drained before the WG flag
        if (tid == 0){
            coh_store_u32(wgflag, w + 1);
        }
        if (wv == 0){
            const int target = w + 1;
            int guard = 0;
            for(;;){
                unsigned int v = (lane < 16)
                    ? coh_load_u32(bgflags + lane)          // 16 WG flags of this bg
                    : (unsigned int)target;
                if (__all((int)v >= target)) break;
                if (++guard > (1<<18)) break;               // hang guard (co-resident => unused)
            }
        }
        __syncthreads();
    }
}

extern "C" void kernel_launch(void* const* d_in, const int* in_sizes, int n_in,
                              void* d_out, int out_size, void* d_ws, size_t ws_size,
                              hipStream_t stream) {
    const int*   x      = (const int*)  d_in[0];
    const float* e01    = (const float*)d_in[1];
    const float* p01    = (const float*)d_in[2];
    const float* f01w   = (const float*)d_in[3];
    const float* f01b   = (const float*)d_in[4];
    const float* f02w   = (const float*)d_in[5];
    const float* f02b   = (const float*)d_in[6];
    const float* f03w   = (const float*)d_in[7];
    const float* f03b   = (const float*)d_in[8];
    const float* Wih0   = (const float*)d_in[9];
    const float* WihR   = (const float*)d_in[10];  // [3][1024][256]
    const float* Whh    = (const float*)d_in[11];  // [4][1024][256]
    const float* bih    = (const float*)d_in[12];
    const float* bhh    = (const float*)d_in[13];
    float* y = (float*)d_out;

    // workspace carve
    float* s_buf = (float*)d_ws;                          // 1,310,720 f
    float* ssum  = s_buf + (size_t)S_LEN*B_N*E_N;         // 1,280 f
    float* bsum  = ssum + B_N*E_N;                        // 4,096 f
    float* Cst   = bsum + L_N*G4;                         // 131,072 f
    int*   flags = (int*)(Cst + (size_t)L_N*B_N*H_N);     // 512 i
    unsigned short* Hbuf = (unsigned short*)(flags + 512);          // 262,144 us
    unsigned short* WbHH = Hbuf + (size_t)L_N*2*B_N*H_N;            // 1,048,576 us
    unsigned short* WbIH = WbHH + (size_t)L_N*G4*H_N;               // 786,432 us

    // weight conversion
    k_cvt<<<dim3(4096), dim3(256), 0, stream>>>(Whh,  WbHH, L_N*G4*H_N);
    k_cvt<<<dim3(3072), dim3(256), 0, stream>>>(WihR, WbIH, (L_N-1)*G4*H_N);

    // prologue
    k_prep_s<<<dim3((S_LEN*B_N)/256), dim3(256), 0, stream>>>(x, e01, p01, f01w, f01b, s_buf);
    k_ssum  <<<dim3(B_N), dim3(256), 0, stream>>>(s_buf, ssum);
    k_init  <<<dim3(B_N), dim3(1024), 0, stream>>>(ssum, f02w, f02b, f03w, f03b, Hbuf, Cst);
    k_bias  <<<dim3(16), dim3(256), 0, stream>>>(bih, bhh, bsum, flags);

    // persistent wavefront LSTM (one dispatch). Try cooperative launch first;
    // on ANY launch error fall back to a plain launch (the sync protocol is
    // flag+guard based and only needs de-facto co-residency: 128 WGs on 256 CUs).
    {
        const float* s_p = s_buf;
        const unsigned short* wih_p = WbIH;
        const unsigned short* whh_p = WbHH;
        const float* wih0_p = Wih0;
        const float* bsum_p = bsum;
        unsigned short* hbuf_p = Hbuf;
        const float* c_p = Cst;
        float* y_p = y;
        int* flags_p = flags;
        void* args[] = { &s_p, &wih_p, &whh_p, &wih0_p, &bsum_p, &hbuf_p, &c_p, &y_p, &flags_p };
        hipError_t cerr = hipLaunchCooperativeKernel(reinterpret_cast<const void*>(&k_lstm),
                                                     dim3(128), dim3(256), args, 0, stream);
        if (cerr != hipSuccess){
            k_lstm<<<dim3(128), dim3(256), 0, stream>>>(s_buf, WbIH, WbHH, Wih0, bsum,
                                                        Hbuf, Cst, y, flags);
        }
    }
}

// Round 12
// 3839.323 us; speedup vs baseline: 3.0889x; 3.0889x over previous
//
#include <hip/hip_runtime.h>
#include <stdint.h>

#define S_LEN 1024
#define B_N   128
#define E_N   10
#define H_N   256
#define L_N   4
#define G4    1024   // 4*H

using short8 = __attribute__((ext_vector_type(8))) short;
using f32x4  = __attribute__((ext_vector_type(4))) float;

__device__ __forceinline__ unsigned short f2bf(float x){
    unsigned int u = __builtin_bit_cast(unsigned int, x);
    u = (u + 0x7FFFu + ((u >> 16) & 1u)) >> 16;   // RNE
    return (unsigned short)u;
}

__device__ __forceinline__ float fast_sig(float x){
    return 1.f/(1.f + __expf(-x));
}
__device__ __forceinline__ float fast_tanh(float x){
    float xc = fminf(fmaxf(x, -15.f), 15.f);
    float e = __expf(-2.f*xc);
    return (1.f - e)/(1.f + e);
}

// ---- convert f32 weights -> bf16 ----
__global__ void k_cvt(const float* __restrict__ src, unsigned short* __restrict__ dst, int n){
    int i = blockIdx.x*256 + threadIdx.x;
    if (i < n) dst[i] = f2bf(src[i]);
}

// ---- s[t][b][e] = relu((e01[x]+p01[t]) @ f01_w.T + f01_b) ----
__global__ void k_prep_s(const int* __restrict__ x, const float* __restrict__ e01,
                         const float* __restrict__ p01, const float* __restrict__ f01w,
                         const float* __restrict__ f01b, float* __restrict__ s){
    int idx = blockIdx.x*256 + threadIdx.x;   // t*128+b
    int t = idx >> 7;
    int tok = x[idx];
    float v[E_N];
    #pragma unroll
    for (int e=0;e<E_N;e++) v[e] = e01[tok*E_N+e] + p01[t*E_N+e];
    #pragma unroll
    for (int eo=0;eo<E_N;eo++){
        float a = f01b[eo];
        #pragma unroll
        for (int e=0;e<E_N;e++) a += v[e]*f01w[eo*E_N+e];
        s[(size_t)idx*E_N+eo] = a > 0.f ? a : 0.f;
    }
}

// ---- ssum[b][e] = sum_t s[t][b][e] ----
__global__ void k_ssum(const float* __restrict__ s, float* __restrict__ ssum){
    __shared__ float red[256][E_N];
    int b = blockIdx.x; int tid = threadIdx.x;
    float acc[E_N] = {};
    for (int t = tid; t < S_LEN; t += 256){
        const float* p = s + ((size_t)t*B_N + b)*E_N;
        #pragma unroll
        for (int e=0;e<E_N;e++) acc[e] += p[e];
    }
    #pragma unroll
    for (int e=0;e<E_N;e++) red[tid][e] = acc[e];
    __syncthreads();
    for (int st=128; st>0; st>>=1){
        if (tid < st){
            #pragma unroll
            for (int e=0;e<E_N;e++) red[tid][e] += red[tid+st][e];
        }
        __syncthreads();
    }
    if (tid < E_N) ssum[b*E_N+tid] = red[0][tid];
}

// ---- h0/c0 (relu MLPs on ssum), scatter into state buffers ----
__global__ void k_init(const float* __restrict__ ssum, const float* __restrict__ f02w,
                       const float* __restrict__ f02b, const float* __restrict__ f03w,
                       const float* __restrict__ f03b,
                       unsigned short* __restrict__ Hbuf, float* __restrict__ C){
    int b = blockIdx.x, j = threadIdx.x;   // j in [0,1024)
    float sv[E_N];
    #pragma unroll
    for (int e=0;e<E_N;e++) sv[e] = ssum[b*E_N+e];
    float h = f02b[j], c = f03b[j];
    #pragma unroll
    for (int e=0;e<E_N;e++){ h += sv[e]*f02w[j*E_N+e]; c += sv[e]*f03w[j*E_N+e]; }
    h = h > 0.f ? h : 0.f;
    c = c > 0.f ? c : 0.f;
    int l = j >> 8, k = j & 255;
    // layer l is first read at wall-step w=l from parity (l&1)
    Hbuf[(((size_t)l*2 + (l&1))*B_N + b)*H_N + k] = f2bf(h);
    C[((size_t)l*B_N + b)*H_N + k] = c;
}

// ---- bias sum + zero the sync flags ----
__global__ void k_bias(const float* __restrict__ bih, const float* __restrict__ bhh,
                       float* __restrict__ bsum, int* __restrict__ flags){
    int i = blockIdx.x*256 + threadIdx.x;   // 4096
    bsum[i] = bih[i] + bhh[i];
    if (i < 512) flags[i] = 0;
}

// ---- coherence-point (sc0 sc1) access helpers ----
__device__ __forceinline__ void coh_load2(const unsigned short* p0, uint4& a0, uint4& a1){
    asm volatile(
        "global_load_dwordx4 %0, %2, off sc0 sc1\n\t"
        "global_load_dwordx4 %1, %3, off sc0 sc1\n\t"
        "s_waitcnt vmcnt(0)"
        : "=&v"(a0), "=&v"(a1)
        : "v"(p0), "v"(p0 + 8)
        : "memory");
}
__device__ __forceinline__ void coh_load4(const unsigned short* p0, const unsigned short* p1,
                                          uint4& a0, uint4& a1, uint4& b0, uint4& b1){
    asm volatile(
        "global_load_dwordx4 %0, %4, off sc0 sc1\n\t"
        "global_load_dwordx4 %1, %5, off sc0 sc1\n\t"
        "global_load_dwordx4 %2, %6, off sc0 sc1\n\t"
        "global_load_dwordx4 %3, %7, off sc0 sc1\n\t"
        "s_waitcnt vmcnt(0)"
        : "=&v"(a0), "=&v"(a1), "=&v"(b0), "=&v"(b1)
        : "v"(p0), "v"(p0 + 8), "v"(p1), "v"(p1 + 8)
        : "memory");
}
__device__ __forceinline__ void coh_store4_short(unsigned short* p,
    unsigned int v0, unsigned int v1, unsigned int v2, unsigned int v3){
    // 4 batch rows, row stride 256 shorts = 512 B
    asm volatile(
        "global_store_short %0, %1, off sc0 sc1\n\t"
        "global_store_short %0, %2, off offset:512 sc0 sc1\n\t"
        "global_store_short %0, %3, off offset:1024 sc0 sc1\n\t"
        "global_store_short %0, %4, off offset:1536 sc0 sc1"
        :: "v"(p), "v"(v0), "v"(v1), "v"(v2), "v"(v3) : "memory");
}
__device__ __forceinline__ void coh_store_u32(int* p, int v){
    asm volatile("global_store_dword %0, %1, off sc0 sc1" :: "v"(p), "v"(v) : "memory");
}
__device__ __forceinline__ unsigned int coh_load_u32(const int* p){
    unsigned int v;
    asm volatile("global_load_dword %0, %1, off sc0 sc1\n\ts_waitcnt vmcnt(0)"
                 : "=v"(v) : "v"(p) : "memory");
    return v;
}
__device__ __forceinline__ void drain_vmem(){
    asm volatile("s_waitcnt vmcnt(0)" ::: "memory");
}

// ---- persistent wavefront LSTM ----
// grid 128 WGs: bg = bid&7, kj = (bid>>3)&3, l = bid>>5 ; block 256 = 4 waves.
// Wave owns 16 k-cols x 4 gates; weights persistent in VGPRs (~390 regs, 1 wave/SIMD).
// h/x staged ONCE per WG into LDS (coalesced sc0sc1); in-register cell update.
// Sync: twice-proven block-level flag protocol.
__global__ __launch_bounds__(256, 1) void k_lstm(
    const float* __restrict__ s,            // [S][B][E] f32
    const unsigned short* __restrict__ Wih, // [3][1024][256] bf16 (layers 1..3)
    const unsigned short* __restrict__ Whh, // [4][1024][256] bf16
    const float* __restrict__ Wih0,         // [1024][10] f32
    const float* __restrict__ bsum,         // [4][1024] f32
    unsigned short* __restrict__ Hbuf,      // [4][2][128][256] bf16
    const float* __restrict__ C,            // [4][128][256] f32 (init only)
    float* __restrict__ y,                  // [128][1024] f32 out
    int* flags)                             // [8][16] per-WG step flags
{
    __shared__ unsigned short hx[16*264];   // h tile (stride 264 -> 2-way LDS aliasing, free)
    __shared__ unsigned short xx[16*264];   // x tile (layers>=1)
    __shared__ float xs[16*E_N];            // layer-0 s tile

    const int bid = blockIdx.x;
    const int bg = bid & 7, kj = (bid >> 3) & 3, l = bid >> 5;
    const int tid = threadIdx.x;
    const int wv = tid >> 6, lane = tid & 63;
    const int cl = lane & 15, kg = lane >> 4;
    const int b0 = bg*16;
    const int kb = kj*64 + wv*16;           // wave's 16-col k base
    const size_t BH = (size_t)B_N * H_N;
    const int lm1 = (l > 0) ? (l - 1) : 0;

    // ---- per-gate bias (into MFMA C-init) ----
    float bia[4];
    #pragma unroll
    for (int g=0; g<4; g++) bia[g] = bsum[l*G4 + g*256 + kb + cl];

    // ---- weights -> persistent VGPRs (B-frag: col=lane&15, k=(lane>>4)*8+j) ----
    short8 whh[4][8];
    #pragma unroll
    for (int g=0; g<4; g++){
        const unsigned short* pr = Whh + ((size_t)l*G4 + g*256 + kb + cl)*H_N + kg*8;
        #pragma unroll
        for (int kt=0; kt<8; kt++) whh[g][kt] = *(const short8*)(pr + kt*32);
    }
    short8 wih[4][8];
    float w0[4][E_N];
    if (l > 0){
        #pragma unroll
        for (int g=0; g<4; g++){
            const unsigned short* pr = Wih + ((size_t)lm1*G4 + g*256 + kb + cl)*H_N + kg*8;
            #pragma unroll
            for (int kt=0; kt<8; kt++) wih[g][kt] = *(const short8*)(pr + kt*32);
        }
    } else {
        #pragma unroll
        for (int g=0; g<4; g++)
            #pragma unroll
            for (int e=0; e<E_N; e++)
                w0[g][e] = Wih0[(g*256 + kb + cl)*E_N + e];
    }

    // ---- private cell state: (batch=kg*4+r, col=kb+cl), 4 per lane ----
    float c[4];
    #pragma unroll
    for (int r=0; r<4; r++)
        c[r] = C[((size_t)l*B_N + b0 + kg*4 + r)*H_N + kb + cl];

    int* const wgflag = flags + bg*16 + l*4 + kj;       // one flag per WG
    const int* const bgflags = flags + bg*16;

    unsigned short* const hstore_base = Hbuf + (size_t)l*2*BH + (size_t)(b0+kg*4)*H_N + kb + cl;

    for (int w = 0; w < S_LEN + L_N - 1; ++w){
        const int t = w - l;
        const int p = w & 1;
        if (t >= 0 && t < S_LEN){
            // ---- stage h (and x) tiles into LDS, once per WG, coalesced sc0sc1 ----
            {
                const int r = tid >> 4, cs = tid & 15;
                const unsigned short* srcH = Hbuf + ((size_t)(l*2 + p))*BH + (size_t)(b0+r)*H_N + cs*16;
                uint4 a0, a1, x0, x1;
                if (l > 0){
                    const unsigned short* srcX = Hbuf + ((size_t)(lm1*2 + p))*BH + (size_t)(b0+r)*H_N + cs*16;
                    coh_load4(srcH, srcX, a0, a1, x0, x1);
                    *(uint4*)&xx[r*264 + cs*16]     = x0;
                    *(uint4*)&xx[r*264 + cs*16 + 8] = x1;
                } else {
                    coh_load2(srcH, a0, a1);
                    if (tid < 16*E_N)
                        xs[tid] = s[((size_t)t*B_N + b0 + tid/E_N)*E_N + (tid%E_N)];
                }
                *(uint4*)&hx[r*264 + cs*16]     = a0;
                *(uint4*)&hx[r*264 + cs*16 + 8] = a1;
            }
            __syncthreads();

            f32x4 acc[4];
            #pragma unroll
            for (int g=0; g<4; g++) acc[g] = (f32x4){bia[g], bia[g], bia[g], bia[g]};

            // A-frag: row=lane&15 (batch cl), k=(lane>>4)*8+j ; k-block kt*32
            short8 ah[8];
            #pragma unroll
            for (int kt=0; kt<8; kt++) ah[kt] = *(const short8*)&hx[cl*264 + kt*32 + kg*8];
            #pragma unroll
            for (int g=0; g<4; g++)
                #pragma unroll
                for (int kt=0; kt<8; kt++)
                    acc[g] = __builtin_amdgcn_mfma_f32_16x16x32_bf16(ah[kt], whh[g][kt], acc[g], 0,0,0);

            if (l > 0){
                short8 ax[8];
                #pragma unroll
                for (int kt=0; kt<8; kt++) ax[kt] = *(const short8*)&xx[cl*264 + kt*32 + kg*8];
                #pragma unroll
                for (int g=0; g<4; g++)
                    #pragma unroll
                    for (int kt=0; kt<8; kt++)
                        acc[g] = __builtin_amdgcn_mfma_f32_16x16x32_bf16(ax[kt], wih[g][kt], acc[g], 0,0,0);
            } else {
                #pragma unroll
                for (int g=0; g<4; g++)
                    #pragma unroll
                    for (int r=0; r<4; r++){
                        float v = acc[g][r];
                        const int br = kg*4 + r;
                        #pragma unroll
                        for (int e=0; e<E_N; e++) v += xs[br*E_N + e]*w0[g][e];
                        acc[g][r] = v;
                    }
            }

            // ---- in-register cell update (i,f,g,o of one element live in same lane/reg) ----
            unsigned int hbits[4];
            float hval[4];
            #pragma unroll
            for (int r=0; r<4; r++){
                float gi = fast_sig(acc[0][r]);
                float gf = fast_sig(acc[1][r]);
                float gg = fast_tanh(acc[2][r]);
                float go = fast_sig(acc[3][r]);
                c[r] = gf*c[r] + gi*gg;
                float hn = go*fast_tanh(c[r]);
                hval[r] = hn;
                hbits[r] = f2bf(hn);
            }
            coh_store4_short(hstore_base + (size_t)(p^1)*BH,
                             hbits[0], hbits[1], hbits[2], hbits[3]);
            if (t == S_LEN-1){
                #pragma unroll
                for (int r=0; r<4; r++)
                    y[(size_t)(b0+kg*4+r)*G4 + l*H_N + kb + cl] = hval[r];
            }
        }
        // ---- block-level sync protocol (proven rounds 3 & 9) ----
        drain_vmem();          // every wave: its h stores acked at coherence point
        __syncthreads();       // all 4 waves drained before the WG flag
        if (tid == 0){
            coh_store_u32(wgflag, w + 1);
        }
        if (wv == 0){
            const int target = w + 1;
            int guard = 0;
            for(;;){
                unsigned int v = (lane < 16)
                    ? coh_load_u32(bgflags + lane)          // 16 WG flags of this bg
                    : (unsigned int)target;
                if (__all((int)v >= target)) break;
                if (++guard > (1<<18)) break;               // hang guard (co-resident => unused)
            }
        }
        __syncthreads();
    }
}

extern "C" void kernel_launch(void* const* d_in, const int* in_sizes, int n_in,
                              void* d_out, int out_size, void* d_ws, size_t ws_size,
                              hipStream_t stream) {
    const int*   x      = (const int*)  d_in[0];
    const float* e01    = (const float*)d_in[1];
    const float* p01    = (const float*)d_in[2];
    const float* f01w   = (const float*)d_in[3];
    const float* f01b   = (const float*)d_in[4];
    const float* f02w   = (const float*)d_in[5];
    const float* f02b   = (const float*)d_in[6];
    const float* f03w   = (const float*)d_in[7];
    const float* f03b   = (const float*)d_in[8];
    const float* Wih0   = (const float*)d_in[9];
    const float* WihR   = (const float*)d_in[10];  // [3][1024][256]
    const float* Whh    = (const float*)d_in[11];  // [4][1024][256]
    const float* bih    = (const float*)d_in[12];
    const float* bhh    = (const float*)d_in[13];
    float* y = (float*)d_out;

    // workspace carve
    float* s_buf = (float*)d_ws;                          // 1,310,720 f
    float* ssum  = s_buf + (size_t)S_LEN*B_N*E_N;         // 1,280 f
    float* bsum  = ssum + B_N*E_N;                        // 4,096 f
    float* Cst   = bsum + L_N*G4;                         // 131,072 f
    int*   flags = (int*)(Cst + (size_t)L_N*B_N*H_N);     // 512 i
    unsigned short* Hbuf = (unsigned short*)(flags + 512);          // 262,144 us
    unsigned short* WbHH = Hbuf + (size_t)L_N*2*B_N*H_N;            // 1,048,576 us
    unsigned short* WbIH = WbHH + (size_t)L_N*G4*H_N;               // 786,432 us

    // weight conversion
    k_cvt<<<dim3(4096), dim3(256), 0, stream>>>(Whh,  WbHH, L_N*G4*H_N);
    k_cvt<<<dim3(3072), dim3(256), 0, stream>>>(WihR, WbIH, (L_N-1)*G4*H_N);

    // prologue
    k_prep_s<<<dim3((S_LEN*B_N)/256), dim3(256), 0, stream>>>(x, e01, p01, f01w, f01b, s_buf);
    k_ssum  <<<dim3(B_N), dim3(256), 0, stream>>>(s_buf, ssum);
    k_init  <<<dim3(B_N), dim3(1024), 0, stream>>>(ssum, f02w, f02b, f03w, f03b, Hbuf, Cst);
    k_bias  <<<dim3(16), dim3(256), 0, stream>>>(bih, bhh, bsum, flags);

    // persistent wavefront LSTM (one dispatch). Cooperative if accepted,
    // else plain launch (flag+guard sync only needs de-facto co-residency:
    // 128 WGs on 256 CUs).
    {
        const float* s_p = s_buf;
        const unsigned short* wih_p = WbIH;
        const unsigned short* whh_p = WbHH;
        const float* wih0_p = Wih0;
        const float* bsum_p = bsum;
        unsigned short* hbuf_p = Hbuf;
        const float* c_p = Cst;
        float* y_p = y;
        int* flags_p = flags;
        void* args[] = { &s_p, &wih_p, &whh_p, &wih0_p, &bsum_p, &hbuf_p, &c_p, &y_p, &flags_p };
        hipError_t cerr = hipLaunchCooperativeKernel(reinterpret_cast<const void*>(&k_lstm),
                                                     dim3(128), dim3(256), args, 0, stream);
        if (cerr != hipSuccess){
            k_lstm<<<dim3(128), dim3(256), 0, stream>>>(s_buf, WbIH, WbHH, Wih0, bsum,
                                                        Hbuf, Cst, y, flags);
        }
    }
}